// Round 10
// baseline (132.385 us; speedup 1.0000x reference)
//
#include <hip/hip_runtime.h>
#include <stdint.h>

typedef _Float16 f16;
typedef __attribute__((ext_vector_type(8))) _Float16 f16x8;
typedef __attribute__((ext_vector_type(4))) float f32x4;
typedef __attribute__((ext_vector_type(2))) float fv2;
typedef __attribute__((ext_vector_type(4))) float fv4;

#define H0 64
#define W0 128
#define NPIX 8192   // H0*W0
#define KD 256
#define NCAT 10880  // 8192 + 2048 + 512 + 128
#define OFF1 8192
#define OFF2 10240
#define OFF3 10752
#define CAP0 640
#define CAP1 2048
#define PL1OFF (32 * CAP0)          // 20480 ints
#define PLTOT (PL1OFF + 8 * CAP1)   // 36864 ints
#define ZTOT (64 + PLTOT + 64)      // cnt(64) + plist + pad

// Fragment-native operand layout: X[kk][row][32]; a 16-lane frag load is one
// contiguous 1KB global_load_dwordx4 from L2 (r9 layout, kept).

// ---------------------------------------------------------------------------
// 1) fused pre-pass: transpose+cvt both fmaps into frag layout, pooled
//    feature rows, zero cnt+plist. grid = 1024 + 336 + 145 = 1505
// ---------------------------------------------------------------------------
__global__ __launch_bounds__(256) void fused_pre(const float* __restrict__ in0,
                                                 const float* __restrict__ in1,
                                                 f16* __restrict__ At,
                                                 f16* __restrict__ Bt,
                                                 int* __restrict__ cnt) {
  __shared__ f16 tile[64][65];
  int bid = blockIdx.x;
  int t = threadIdx.x;

  if (bid < 1024) {                       // ---- transpose + cvt ----
    const float* in = (bid < 512) ? in0 : in1;
    f16* out = (bid < 512) ? At : Bt;
    size_t NR = (bid < 512) ? NPIX : NCAT;
    int bx = bid & 511;
    int m0 = (bx & 127) * 64;
    int d0 = (bx >> 7) * 64;
    int a = t & 63, b = t >> 6;
#pragma unroll
    for (int i = 0; i < 16; ++i) {
      int d = b + i * 4;
      tile[a][d] = (f16)in[(size_t)(d0 + d) * NPIX + m0 + a];
    }
    __syncthreads();
#pragma unroll
    for (int i = 0; i < 16; ++i) {
      int m = b + i * 4;
      int d = d0 + a;
      out[((size_t)(d >> 5) * NR + (m0 + m)) * 32 + (d & 31)] = tile[m][a];
    }
  } else if (bid < 1360) {                // ---- pooled feature rows ----
    int idx = (bid - 1024) * 256 + t;     // 0..86015
    float acc[8] = {0, 0, 0, 0, 0, 0, 0, 0};
    int r, dc;
    if (idx < 65536) {                    // lev1: 2048 rows, 2x2
      int r1 = idx & 2047; dc = idx >> 11; r = r1;
      int y = r1 >> 6, x = r1 & 63;
#pragma unroll
      for (int e = 0; e < 8; ++e) {
        const float* p = in1 + (size_t)(dc * 8 + e) * NPIX + (y * 2) * W0 + x * 2;
        fv2 s0 = *(const fv2*)p;
        fv2 s1 = *(const fv2*)(p + W0);
        acc[e] = (s0[0] + s0[1] + s1[0] + s1[1]) * 0.25f;
      }
    } else if (idx < 81920) {             // lev2: 512 rows, 4x4
      int i2 = idx - 65536;
      int r2 = i2 & 511; dc = i2 >> 9; r = 2048 + r2;
      int y = r2 >> 5, x = r2 & 31;
#pragma unroll
      for (int e = 0; e < 8; ++e) {
        const float* p = in1 + (size_t)(dc * 8 + e) * NPIX + (y * 4) * W0 + x * 4;
        float s = 0.f;
#pragma unroll
        for (int h = 0; h < 4; ++h) {
          fv4 v = *(const fv4*)(p + h * W0);
          s += v[0] + v[1] + v[2] + v[3];
        }
        acc[e] = s * 0.0625f;
      }
    } else {                              // lev3: 128 rows, 8x8
      int i3 = idx - 81920;
      int r3 = i3 & 127; dc = i3 >> 7; r = 2560 + r3;
      int y = r3 >> 4, x = r3 & 15;
#pragma unroll
      for (int e = 0; e < 8; ++e) {
        const float* p = in1 + (size_t)(dc * 8 + e) * NPIX + (y * 8) * W0 + x * 8;
        float s = 0.f;
#pragma unroll
        for (int h = 0; h < 8; ++h) {
          fv4 v0 = *(const fv4*)(p + h * W0);
          fv4 v1 = *(const fv4*)(p + h * W0 + 4);
          s += v0[0] + v0[1] + v0[2] + v0[3] + v1[0] + v1[1] + v1[2] + v1[3];
        }
        acc[e] = s * 0.015625f;
      }
    }
    f16x8 o;
#pragma unroll
    for (int e = 0; e < 8; ++e) o[e] = (f16)acc[e];
    *(f16x8*)(Bt + ((size_t)(dc >> 2) * NCAT + 8192 + r) * 32 + (dc & 3) * 8) = o;
  } else {                                // ---- zero cnt + plist ----
    int idx = (bid - 1360) * 256 + t;
    if (idx < ZTOT) cnt[idx] = 0;
  }
}

// ---------------------------------------------------------------------------
// 2) bucket build: per-pixel window metadata + bucket lists (L0: 32 buckets
//    of 16x16 X0/Y0 cells; L1: 8). Atomic order nondeterministic but the SET
//    per bucket is deterministic; outputs don't depend on slot order.
// ---------------------------------------------------------------------------
__global__ __launch_bounds__(256) void bucket_build(const float* __restrict__ coords,
                                                    int2* __restrict__ meta,
                                                    int* __restrict__ cnt) {
  int* plist = cnt + 64;
  int m = blockIdx.x * 256 + threadIdx.x;   // 32 blocks
  float cx = coords[m];
  float cy = coords[NPIX + m];
  int X0l[4], Y0l[4];
  int mx = 0, my = 0;
#pragma unroll
  for (int lev = 0; lev < 4; ++lev) {
    float inv = 1.0f / (float)(1 << lev);
    int X0 = (int)floorf(cx * inv) - 4;     // identical expr in corr_sample
    int Y0 = (int)floorf(cy * inv) - 4;
    X0l[lev] = X0; Y0l[lev] = Y0;
    mx |= (X0 & 0xff) << (8 * lev);
    my |= (Y0 & 0xff) << (8 * lev);
  }
  meta[m] = make_int2(mx, my);
  {
    int bx = min(max(X0l[0], 0), 127) >> 4;
    int by = min(max(Y0l[0], 0), 63) >> 4;
    int b = by * 8 + bx;
    int s = atomicAdd(&cnt[b], 1);
    if (s < CAP0) plist[b * CAP0 + s] = m;
  }
  {
    int bx = min(max(X0l[1], 0), 63) >> 4;
    int by = min(max(Y0l[1], 0), 31) >> 4;
    int b = by * 4 + bx;
    int s = atomicAdd(&cnt[32 + b], 1);
    if (s < CAP1) plist[PL1OFF + b * CAP1 + s] = m;
  }
}

// ---------------------------------------------------------------------------
// 3) bucketed GEMM for levels 0 and 1: block = 32 bucket-pixels x one
//    half-region (13 y-strips x 32 x) x K=256. A gathered via plist; B
//    coalesced frag loads; no LDS, no barriers; masked scatter into W.
//    grid = 32*20*2 (L0) + 8*64*2 (L1) = 2304, most exit on cnt.
// ---------------------------------------------------------------------------
__global__ __launch_bounds__(256, 2) void gemm_bucket(const f16* __restrict__ At,
                                                      const f16* __restrict__ Bt,
                                                      const int* __restrict__ cnt,
                                                      const int2* __restrict__ meta,
                                                      f16* __restrict__ Wbuf) {
  const int* plist = cnt + 64;
  int bid = blockIdx.x;
  int lev, b, mg, half;
  if (bid < 1280) { lev = 0; b = bid / 40; int r = bid % 40; mg = r >> 1; half = r & 1; }
  else { lev = 1; int i = bid - 1280; b = i / 128; int r = i % 128; mg = r >> 1; half = r & 1; }

  int CAP   = lev ? CAP1 : CAP0;
  int cb    = min(cnt[lev ? 32 + b : b], CAP);
  if (mg * 32 >= cb) return;
  int Hl    = lev ? 32 : 64;
  int Wmap  = lev ? 64 : 128;
  int bx    = lev ? (b & 3) : (b & 7);
  int by    = lev ? (b >> 2) : (b >> 3);
  int x0 = bx * 16, y0 = by * 16;
  int NY = min(25, Hl - y0);
  int rowbase = lev ? 8192 : 0;
  int pbase = (lev ? PL1OFF + b * CAP1 : b * CAP0) + mg * 32;

  int t = threadIdx.x;
  int lane = t & 63;
  int w = t >> 6;               // wave 0..3
  int lr = lane & 15;
  int ko = lane >> 4;

  int prow[2];
  prow[0] = plist[pbase + lr];
  prow[1] = plist[pbase + 16 + lr];

  bool vst[4];
  int brow[4];
#pragma unroll
  for (int st = 0; st < 4; ++st) {
    int q = w + 4 * st;
    int yl = half * 13 + q;
    vst[st] = (q < (half ? 12 : 13)) && (yl < NY);
    int ylc = min(yl, NY - 1);  // clamped: always-valid load, masked at write
    brow[st] = rowbase + (y0 + ylc) * Wmap + x0 + lr;
  }

  f16x8 af[2][2], bf[2][8];
#define BLD(s_, kk_)                                                           \
  do {                                                                         \
    const f16* ap = At + (size_t)(kk_) * (NPIX * 32) + ko * 8;                 \
    const f16* bp = Bt + (size_t)(kk_) * (NCAT * 32) + ko * 8;                 \
    af[s_][0] = *(const f16x8*)(ap + prow[0] * 32);                            \
    af[s_][1] = *(const f16x8*)(ap + prow[1] * 32);                            \
    _Pragma("unroll")                                                          \
    for (int st = 0; st < 4; ++st) {                                           \
      bf[s_][st * 2]     = *(const f16x8*)(bp + (size_t)brow[st] * 32);        \
      bf[s_][st * 2 + 1] = *(const f16x8*)(bp + (size_t)(brow[st] + 16) * 32); \
    }                                                                          \
  } while (0)

  f32x4 acc[8][2];
#pragma unroll
  for (int i = 0; i < 8; ++i)
#pragma unroll
    for (int j = 0; j < 2; ++j) acc[i][j] = (f32x4){0.f, 0.f, 0.f, 0.f};

  BLD(0, 0);
  BLD(1, 1);
#pragma unroll
  for (int kk = 0; kk < 8; ++kk) {
    const int cur = kk & 1;
#pragma unroll
    for (int nf = 0; nf < 8; ++nf)
#pragma unroll
      for (int mi = 0; mi < 2; ++mi)
        acc[nf][mi] = __builtin_amdgcn_mfma_f32_16x16x32_f16(
            af[cur][mi], bf[cur][nf], acc[nf][mi], 0, 0, 0);
    if (kk + 2 < 8) BLD(cur, kk + 2);
  }
#undef BLD

  // ---- masked scatter into W ----
  int pe[2][4];
  int Xp[2][4], Yp[2][4];
  int sh = lev * 8;
#pragma unroll
  for (int mi = 0; mi < 2; ++mi)
#pragma unroll
    for (int r2 = 0; r2 < 4; ++r2) {
      int slot = mg * 32 + mi * 16 + ko * 4 + r2;
      int p = plist[pbase + mi * 16 + ko * 4 + r2];   // padded area valid (zeroed)
      pe[mi][r2] = (slot < cb) ? p : -1;
      int2 mv = meta[p < 0 ? 0 : p];
      Xp[mi][r2] = (int)(signed char)((mv.x >> sh) & 0xff);
      Yp[mi][r2] = (int)(signed char)((mv.y >> sh) & 0xff);
    }
  f16* wl = Wbuf + (size_t)(lev * 100) * NPIX;
#pragma unroll
  for (int st = 0; st < 4; ++st) {
    if (!vst[st]) continue;
    int y = y0 + half * 13 + w + 4 * st;
#pragma unroll
    for (int xc = 0; xc < 2; ++xc) {
      int x = x0 + xc * 16 + lr;
#pragma unroll
      for (int mi = 0; mi < 2; ++mi)
#pragma unroll
        for (int r2 = 0; r2 < 4; ++r2) {
          int p = pe[mi][r2];
          int dy = y - Yp[mi][r2];
          int dx = x - Xp[mi][r2];
          if (p >= 0 && (unsigned)dy < 10u && (unsigned)dx < 10u)
            wl[(size_t)(dy * 10 + dx) * NPIX + p] =
                (f16)(acc[st * 2 + xc][mi][r2] * 0.0625f);
        }
    }
  }
}

// ---------------------------------------------------------------------------
// 4) dense GEMM for levels 2+3 (640 cols): r9 structure, grid 160.
// ---------------------------------------------------------------------------
__global__ __launch_bounds__(256, 2) void gemm_dense(const f16* __restrict__ At,
                                                     const f16* __restrict__ Bt,
                                                     const int2* __restrict__ meta,
                                                     f16* __restrict__ Wbuf) {
  int bid = blockIdx.x;        // 160 = 8 xcd * 4 bmt * 5 bn
  int bm = (((bid & 7) << 2) | ((bid >> 3) & 3)) << 8;
  int bn = OFF2 + ((bid >> 5) << 7);

  int t = threadIdx.x;
  int lane = t & 63;
  int w = t >> 6;
  int lr = lane & 15;
  int ko = lane >> 4;

  const f16* Ab = At + (size_t)(bm + w * 64 + lr) * 32 + ko * 8;
  const f16* Bb = Bt + (size_t)(bn + lr) * 32 + ko * 8;

  f16x8 af[2][4], bf[2][8];
#define LOADK(s, kk)                                                           \
  do {                                                                         \
    const f16* ap = Ab + (size_t)(kk) * (NPIX * 32);                           \
    const f16* bp = Bb + (size_t)(kk) * (NCAT * 32);                           \
    _Pragma("unroll")                                                          \
    for (int i = 0; i < 4; ++i) af[s][i] = *(const f16x8*)(ap + i * 512);      \
    _Pragma("unroll")                                                          \
    for (int i = 0; i < 8; ++i) bf[s][i] = *(const f16x8*)(bp + i * 512);      \
  } while (0)

  f32x4 acc[4][8];
#pragma unroll
  for (int i = 0; i < 4; ++i)
#pragma unroll
    for (int j = 0; j < 8; ++j) acc[i][j] = (f32x4){0.f, 0.f, 0.f, 0.f};

  LOADK(0, 0);
  LOADK(1, 1);
#pragma unroll
  for (int kk = 0; kk < 8; ++kk) {
    const int cur = kk & 1;
#pragma unroll
    for (int mi = 0; mi < 4; ++mi)
#pragma unroll
      for (int ni = 0; ni < 8; ++ni)
        acc[mi][ni] = __builtin_amdgcn_mfma_f32_16x16x32_f16(
            af[cur][mi], bf[cur][ni], acc[mi][ni], 0, 0, 0);
    if (kk + 2 < 8) LOADK(cur, kk + 2);
  }
#undef LOADK

  int lev, n0, wlog;
  if (bn < OFF3) { lev = 2; n0 = bn - OFF2; wlog = 5; }
  else           { lev = 3; n0 = bn - OFF3; wlog = 4; }
  int wmask = (1 << wlog) - 1;
  int yA = n0 >> wlog;
  int yB = (n0 + 127) >> wlog;
  int ycol[8], xcol[8];
#pragma unroll
  for (int ni = 0; ni < 8; ++ni) {
    int n = n0 + ni * 16 + lr;
    ycol[ni] = n >> wlog;
    xcol[ni] = n & wmask;
  }
  f16* wlev = Wbuf + (size_t)(lev * 100) * NPIX;
  int sh = lev * 8;
#pragma unroll
  for (int mi = 0; mi < 4; ++mi)
#pragma unroll
    for (int r2 = 0; r2 < 4; ++r2) {
      int grow = bm + w * 64 + mi * 16 + ko * 4 + r2;
      int2 mv = meta[grow];
      int Y0 = (int)(signed char)((mv.y >> sh) & 0xff);
      if (Y0 <= yB && Y0 + 9 >= yA) {
        int X0 = (int)(signed char)((mv.x >> sh) & 0xff);
        f16* rowp = wlev + grow;
#pragma unroll
        for (int ni = 0; ni < 8; ++ni) {
          int dy = ycol[ni] - Y0;
          int dx = xcol[ni] - X0;
          if ((unsigned)dy < 10u && (unsigned)dx < 10u)
            rowp[(size_t)(dy * 10 + dx) * NPIX] =
                (f16)(acc[mi][ni][r2] * 0.0625f);
        }
      }
    }
}

// ---------------------------------------------------------------------------
// 5) bilinear sampling from compact corner buffer W[lev*100+dy*10+dx][m].
// ---------------------------------------------------------------------------
__global__ __launch_bounds__(256) void corr_sample(const f16* __restrict__ Wbuf,
                                                   const float* __restrict__ coords,
                                                   float* __restrict__ out) {
  int bx = blockIdx.x;            // 288 = 8 xcd * 36
  int xcd = bx & 7;
  int idx = bx >> 3;              // 0..35
  int j = idx % 9;                // window row
  int mc = xcd + 8 * (idx / 9);   // m-chunk 0..31
  int m = mc * 256 + threadIdx.x;
  int lev = blockIdx.z;
  int Hl = H0 >> lev, Wl = W0 >> lev;

  float cx = coords[m];
  float cy = coords[NPIX + m];
  float inv = 1.0f / (float)(1 << lev);
  float xb = cx * inv, yb = cy * inv;
  float fx = floorf(xb), fy = floorf(yb);
  int X0 = (int)fx - 4, Y0 = (int)fy - 4;   // matches bucket_build meta exactly
  float wx1 = xb - fx, wx0 = 1.0f - wx1;
  float wy1 = yb - fy, wy0 = 1.0f - wy1;

  const f16* wb = Wbuf + (size_t)(lev * 100) * NPIX + m;
  float* op = out + ((size_t)lev * 81 + (size_t)j * 9) * NPIX + m;

  float cur[10], nxt[10];
  auto loadrow = [&](float* row, int jr) {
    int y = Y0 + jr;
    bool yin = (unsigned)y < (unsigned)Hl;
#pragma unroll
    for (int i = 0; i < 10; ++i) {
      int x = X0 + i;
      bool in = yin && ((unsigned)x < (unsigned)Wl);
      row[i] = in ? (float)wb[(size_t)(jr * 10 + i) * NPIX] : 0.0f;
    }
  };
  loadrow(cur, j);
  loadrow(nxt, j + 1);
#pragma unroll
  for (int i = 0; i < 9; ++i) {
    float v = wy0 * (wx0 * cur[i] + wx1 * cur[i + 1])
            + wy1 * (wx0 * nxt[i] + wx1 * nxt[i + 1]);
    op[(size_t)i * NPIX] = v;
  }
}

// ---------------------------------------------------------------------------
extern "C" void kernel_launch(void* const* d_in, const int* in_sizes, int n_in,
                              void* d_out, int out_size, void* d_ws, size_t ws_size,
                              hipStream_t stream) {
  const float* fmap1  = (const float*)d_in[0];   // [1,256,64,128]
  const float* fmap2  = (const float*)d_in[1];
  const float* coords = (const float*)d_in[2];   // [1,2,64,128]
  float* out = (float*)d_out;                    // [1,324,64,128] fp32

  char* ws = (char*)d_ws;
  size_t offA = 0;
  size_t offB = offA + (size_t)NPIX * KD * 2;    // At: 4 MB
  size_t offW = offB + (size_t)NCAT * KD * 2;    // Bt: 5.57 MB
  size_t offM = offW + (size_t)400 * NPIX * 2;   // W: 6.55 MB
  size_t offC = offM + (size_t)NPIX * 8;         // meta: 64 KB
  size_t need = offC + (size_t)ZTOT * 4;         // cnt+plist: ~148 KB
  if (ws_size < need) return;

  f16*  At   = (f16*)(ws + offA);
  f16*  Bt   = (f16*)(ws + offB);
  f16*  Wbuf = (f16*)(ws + offW);
  int2* meta = (int2*)(ws + offM);
  int*  cnt  = (int*)(ws + offC);

  fused_pre<<<1505, 256, 0, stream>>>(fmap1, fmap2, At, Bt, cnt);
  bucket_build<<<32, 256, 0, stream>>>(coords, meta, cnt);
  gemm_bucket<<<2304, 256, 0, stream>>>(At, Bt, cnt, meta, Wbuf);
  gemm_dense<<<160, 256, 0, stream>>>(At, Bt, meta, Wbuf);
  corr_sample<<<dim3(288, 1, 4), 256, 0, stream>>>(Wbuf, coords, out);
}

// Round 11
// 82.426 us; speedup vs baseline: 1.6061x; 1.6061x over previous
//
#include <hip/hip_runtime.h>
#include <stdint.h>

typedef _Float16 f16;
typedef __attribute__((ext_vector_type(8))) _Float16 f16x8;
typedef __attribute__((ext_vector_type(4))) float f32x4;
typedef __attribute__((ext_vector_type(2))) float fv2;
typedef __attribute__((ext_vector_type(4))) float fv4;

#define H0 64
#define W0 128
#define NPIX 8192   // H0*W0
#define KD 256
#define NCAT 10880  // 8192 + 2048 + 512 + 128
#define OFF1 8192
#define OFF2 10240
#define OFF3 10752
#define CAP0 640
#define CAP1 2048
#define PL1OFF (32 * CAP0)          // 20480 ints
#define PLTOT (PL1OFF + 8 * CAP1)   // 36864 ints
#define ZTOT (64 + PLTOT + 64)      // cnt(64) + plist + pad

// Fragment-native operand layout: X[kk][row][32]; a 16-lane frag load is one
// contiguous 1KB global_load_dwordx4 from L2 (r9 layout, kept).

// ---------------------------------------------------------------------------
// 1) fused pre-pass: transpose+cvt both fmaps into frag layout, pooled
//    feature rows, zero cnt+plist. grid = 1024 + 336 + 145 = 1505
// ---------------------------------------------------------------------------
__global__ __launch_bounds__(256) void fused_pre(const float* __restrict__ in0,
                                                 const float* __restrict__ in1,
                                                 f16* __restrict__ At,
                                                 f16* __restrict__ Bt,
                                                 int* __restrict__ cnt) {
  __shared__ f16 tile[64][65];
  int bid = blockIdx.x;
  int t = threadIdx.x;

  if (bid < 1024) {                       // ---- transpose + cvt ----
    const float* in = (bid < 512) ? in0 : in1;
    f16* out = (bid < 512) ? At : Bt;
    size_t NR = (bid < 512) ? NPIX : NCAT;
    int bx = bid & 511;
    int m0 = (bx & 127) * 64;
    int d0 = (bx >> 7) * 64;
    int a = t & 63, b = t >> 6;
#pragma unroll
    for (int i = 0; i < 16; ++i) {
      int d = b + i * 4;
      tile[a][d] = (f16)in[(size_t)(d0 + d) * NPIX + m0 + a];
    }
    __syncthreads();
#pragma unroll
    for (int i = 0; i < 16; ++i) {
      int m = b + i * 4;
      int d = d0 + a;
      out[((size_t)(d >> 5) * NR + (m0 + m)) * 32 + (d & 31)] = tile[m][a];
    }
  } else if (bid < 1360) {                // ---- pooled feature rows ----
    int idx = (bid - 1024) * 256 + t;     // 0..86015
    float acc[8] = {0, 0, 0, 0, 0, 0, 0, 0};
    int r, dc;
    if (idx < 65536) {                    // lev1: 2048 rows, 2x2
      int r1 = idx & 2047; dc = idx >> 11; r = r1;
      int y = r1 >> 6, x = r1 & 63;
#pragma unroll
      for (int e = 0; e < 8; ++e) {
        const float* p = in1 + (size_t)(dc * 8 + e) * NPIX + (y * 2) * W0 + x * 2;
        fv2 s0 = *(const fv2*)p;
        fv2 s1 = *(const fv2*)(p + W0);
        acc[e] = (s0[0] + s0[1] + s1[0] + s1[1]) * 0.25f;
      }
    } else if (idx < 81920) {             // lev2: 512 rows, 4x4
      int i2 = idx - 65536;
      int r2 = i2 & 511; dc = i2 >> 9; r = 2048 + r2;
      int y = r2 >> 5, x = r2 & 31;
#pragma unroll
      for (int e = 0; e < 8; ++e) {
        const float* p = in1 + (size_t)(dc * 8 + e) * NPIX + (y * 4) * W0 + x * 4;
        float s = 0.f;
#pragma unroll
        for (int h = 0; h < 4; ++h) {
          fv4 v = *(const fv4*)(p + h * W0);
          s += v[0] + v[1] + v[2] + v[3];
        }
        acc[e] = s * 0.0625f;
      }
    } else {                              // lev3: 128 rows, 8x8
      int i3 = idx - 81920;
      int r3 = i3 & 127; dc = i3 >> 7; r = 2560 + r3;
      int y = r3 >> 4, x = r3 & 15;
#pragma unroll
      for (int e = 0; e < 8; ++e) {
        const float* p = in1 + (size_t)(dc * 8 + e) * NPIX + (y * 8) * W0 + x * 8;
        float s = 0.f;
#pragma unroll
        for (int h = 0; h < 8; ++h) {
          fv4 v0 = *(const fv4*)(p + h * W0);
          fv4 v1 = *(const fv4*)(p + h * W0 + 4);
          s += v0[0] + v0[1] + v0[2] + v0[3] + v1[0] + v1[1] + v1[2] + v1[3];
        }
        acc[e] = s * 0.015625f;
      }
    }
    f16x8 o;
#pragma unroll
    for (int e = 0; e < 8; ++e) o[e] = (f16)acc[e];
    *(f16x8*)(Bt + ((size_t)(dc >> 2) * NCAT + 8192 + r) * 32 + (dc & 3) * 8) = o;
  } else {                                // ---- zero cnt + plist ----
    int idx = (bid - 1360) * 256 + t;
    if (idx < ZTOT) cnt[idx] = 0;
  }
}

// ---------------------------------------------------------------------------
// 2) bucket build, LDS-aggregated (G12): 8 blocks x 1024 thr. Per-block LDS
//    histogram -> ONE global atomicAdd per (block,bucket) to reserve a range
//    (per-address chain depth = 8) -> exact-slot scatter. Deterministic set.
// ---------------------------------------------------------------------------
__global__ __launch_bounds__(1024) void bucket_build(const float* __restrict__ coords,
                                                     int2* __restrict__ meta,
                                                     int* __restrict__ cnt) {
  __shared__ int hist[40];
  __shared__ int base[40];
  int* plist = cnt + 64;
  int t = threadIdx.x;
  int m = blockIdx.x * 1024 + t;
  if (t < 40) hist[t] = 0;
  __syncthreads();

  float cx = coords[m];
  float cy = coords[NPIX + m];
  int X0l[2], Y0l[2];
  int mx = 0, my = 0;
#pragma unroll
  for (int lev = 0; lev < 4; ++lev) {
    float inv = 1.0f / (float)(1 << lev);
    int X0 = (int)floorf(cx * inv) - 4;     // identical expr in corr_sample
    int Y0 = (int)floorf(cy * inv) - 4;
    if (lev < 2) { X0l[lev] = X0; Y0l[lev] = Y0; }
    mx |= (X0 & 0xff) << (8 * lev);
    my |= (Y0 & 0xff) << (8 * lev);
  }
  meta[m] = make_int2(mx, my);

  int b0 = (min(max(Y0l[0], 0), 63) >> 4) * 8 + (min(max(X0l[0], 0), 127) >> 4);
  int b1 = (min(max(Y0l[1], 0), 31) >> 4) * 4 + (min(max(X0l[1], 0), 63) >> 4);
  int s0 = atomicAdd(&hist[b0], 1);        // LDS atomics: short chains
  int s1 = atomicAdd(&hist[32 + b1], 1);
  __syncthreads();

  if (t < 40) base[t] = atomicAdd(&cnt[t], hist[t]);   // 8-deep global chains
  __syncthreads();

  int p0 = base[b0] + s0;
  if (p0 < CAP0) plist[b0 * CAP0 + p0] = m;
  int p1 = base[32 + b1] + s1;
  if (p1 < CAP1) plist[PL1OFF + b1 * CAP1 + p1] = m;
}

// ---------------------------------------------------------------------------
// 3) merged GEMM: bid<160 -> dense levels 2+3 (r9 structure); else bucketed
//    levels 0+1 (32-pixel x half-region blocks, masked scatter into W).
//    No LDS, no barriers; frag-native coalesced/gathered register loads.
// ---------------------------------------------------------------------------
__global__ __launch_bounds__(256, 2) void gemm_all(const f16* __restrict__ At,
                                                   const f16* __restrict__ Bt,
                                                   const int* __restrict__ cnt,
                                                   const int2* __restrict__ meta,
                                                   f16* __restrict__ Wbuf) {
  const int* plist = cnt + 64;
  int bid = blockIdx.x;      // 160 dense + 2304 bucket = 2464
  int t = threadIdx.x;
  int lane = t & 63;
  int w = t >> 6;
  int lr = lane & 15;
  int ko = lane >> 4;

  if (bid < 160) {
    // ================= dense path: levels 2+3 =================
    int bm = (((bid & 7) << 2) | ((bid >> 3) & 3)) << 8;
    int bn = OFF2 + ((bid >> 5) << 7);

    const f16* Ab = At + (size_t)(bm + w * 64 + lr) * 32 + ko * 8;
    const f16* Bb = Bt + (size_t)(bn + lr) * 32 + ko * 8;

    f16x8 af[2][4], bf[2][8];
#define LOADK(s, kk)                                                           \
    do {                                                                       \
      const f16* ap = Ab + (size_t)(kk) * (NPIX * 32);                         \
      const f16* bp = Bb + (size_t)(kk) * (NCAT * 32);                         \
      _Pragma("unroll")                                                        \
      for (int i = 0; i < 4; ++i) af[s][i] = *(const f16x8*)(ap + i * 512);    \
      _Pragma("unroll")                                                        \
      for (int i = 0; i < 8; ++i) bf[s][i] = *(const f16x8*)(bp + i * 512);    \
    } while (0)

    f32x4 acc[4][8];
#pragma unroll
    for (int i = 0; i < 4; ++i)
#pragma unroll
      for (int j = 0; j < 8; ++j) acc[i][j] = (f32x4){0.f, 0.f, 0.f, 0.f};

    LOADK(0, 0);
    LOADK(1, 1);
#pragma unroll
    for (int kk = 0; kk < 8; ++kk) {
      const int cur = kk & 1;
#pragma unroll
      for (int mi = 0; mi < 4; ++mi)
#pragma unroll
        for (int ni = 0; ni < 8; ++ni)
          acc[mi][ni] = __builtin_amdgcn_mfma_f32_16x16x32_f16(
              af[cur][mi], bf[cur][ni], acc[mi][ni], 0, 0, 0);
      if (kk + 2 < 8) LOADK(cur, kk + 2);
    }
#undef LOADK

    int lev, n0, wlog;
    if (bn < OFF3) { lev = 2; n0 = bn - OFF2; wlog = 5; }
    else           { lev = 3; n0 = bn - OFF3; wlog = 4; }
    int wmask = (1 << wlog) - 1;
    int yA = n0 >> wlog;
    int yB = (n0 + 127) >> wlog;
    int ycol[8], xcol[8];
#pragma unroll
    for (int ni = 0; ni < 8; ++ni) {
      int n = n0 + ni * 16 + lr;
      ycol[ni] = n >> wlog;
      xcol[ni] = n & wmask;
    }
    f16* wlev = Wbuf + (size_t)(lev * 100) * NPIX;
    int sh = lev * 8;
#pragma unroll
    for (int mi = 0; mi < 4; ++mi)
#pragma unroll
      for (int r2 = 0; r2 < 4; ++r2) {
        int grow = bm + w * 64 + mi * 16 + ko * 4 + r2;
        int2 mv = meta[grow];
        int Y0 = (int)(signed char)((mv.y >> sh) & 0xff);
        if (Y0 <= yB && Y0 + 9 >= yA) {
          int X0 = (int)(signed char)((mv.x >> sh) & 0xff);
          f16* rowp = wlev + grow;
#pragma unroll
          for (int ni = 0; ni < 8; ++ni) {
            int dy = ycol[ni] - Y0;
            int dx = xcol[ni] - X0;
            if ((unsigned)dy < 10u && (unsigned)dx < 10u)
              rowp[(size_t)(dy * 10 + dx) * NPIX] =
                  (f16)(acc[mi][ni][r2] * 0.0625f);
          }
        }
      }
    return;
  }

  // ================= bucket path: levels 0+1 =================
  int bb = bid - 160;
  int lev, b, mg, half;
  if (bb < 1280) { lev = 0; b = bb / 40; int r = bb % 40; mg = r >> 1; half = r & 1; }
  else { lev = 1; int i = bb - 1280; b = i / 128; int r = i % 128; mg = r >> 1; half = r & 1; }

  int CAP   = lev ? CAP1 : CAP0;
  int cb    = min(cnt[lev ? 32 + b : b], CAP);
  if (mg * 32 >= cb) return;
  int Hl    = lev ? 32 : 64;
  int Wmap  = lev ? 64 : 128;
  int bx    = lev ? (b & 3) : (b & 7);
  int by    = lev ? (b >> 2) : (b >> 3);
  int x0 = bx * 16, y0 = by * 16;
  int NY = min(25, Hl - y0);
  int rowbase = lev ? 8192 : 0;
  int pbase = (lev ? PL1OFF + b * CAP1 : b * CAP0) + mg * 32;

  int prow[2];
  prow[0] = plist[pbase + lr] & (NPIX - 1);
  prow[1] = plist[pbase + 16 + lr] & (NPIX - 1);

  bool vst[4];
  int brow[4];
#pragma unroll
  for (int st = 0; st < 4; ++st) {
    int q = w + 4 * st;
    int yl = half * 13 + q;
    vst[st] = (q < (half ? 12 : 13)) && (yl < NY);
    int ylc = min(yl, NY - 1);  // clamped: always-valid load, masked at write
    brow[st] = rowbase + (y0 + ylc) * Wmap + x0 + lr;
  }

  f16x8 af[2][2], bf[2][8];
#define BLD(s_, kk_)                                                           \
  do {                                                                         \
    const f16* ap = At + (size_t)(kk_) * (NPIX * 32) + ko * 8;                 \
    const f16* bp = Bt + (size_t)(kk_) * (NCAT * 32) + ko * 8;                 \
    af[s_][0] = *(const f16x8*)(ap + prow[0] * 32);                            \
    af[s_][1] = *(const f16x8*)(ap + prow[1] * 32);                            \
    _Pragma("unroll")                                                          \
    for (int st = 0; st < 4; ++st) {                                           \
      bf[s_][st * 2]     = *(const f16x8*)(bp + (size_t)brow[st] * 32);        \
      bf[s_][st * 2 + 1] = *(const f16x8*)(bp + (size_t)(brow[st] + 16) * 32); \
    }                                                                          \
  } while (0)

  f32x4 acc[8][2];
#pragma unroll
  for (int i = 0; i < 8; ++i)
#pragma unroll
    for (int j = 0; j < 2; ++j) acc[i][j] = (f32x4){0.f, 0.f, 0.f, 0.f};

  BLD(0, 0);
  BLD(1, 1);
#pragma unroll
  for (int kk = 0; kk < 8; ++kk) {
    const int cur = kk & 1;
#pragma unroll
    for (int nf = 0; nf < 8; ++nf)
#pragma unroll
      for (int mi = 0; mi < 2; ++mi)
        acc[nf][mi] = __builtin_amdgcn_mfma_f32_16x16x32_f16(
            af[cur][mi], bf[cur][nf], acc[nf][mi], 0, 0, 0);
    if (kk + 2 < 8) BLD(cur, kk + 2);
  }
#undef BLD

  // ---- masked scatter into W ----
  int pe[2][4];
  int Xp[2][4], Yp[2][4];
  int sh = lev * 8;
#pragma unroll
  for (int mi = 0; mi < 2; ++mi)
#pragma unroll
    for (int r2 = 0; r2 < 4; ++r2) {
      int slot = mg * 32 + mi * 16 + ko * 4 + r2;
      int p = plist[pbase + mi * 16 + ko * 4 + r2] & (NPIX - 1);
      pe[mi][r2] = (slot < cb) ? p : -1;
      int2 mv = meta[p];
      Xp[mi][r2] = (int)(signed char)((mv.x >> sh) & 0xff);
      Yp[mi][r2] = (int)(signed char)((mv.y >> sh) & 0xff);
    }
  f16* wl = Wbuf + (size_t)(lev * 100) * NPIX;
#pragma unroll
  for (int st = 0; st < 4; ++st) {
    if (!vst[st]) continue;
    int y = y0 + half * 13 + w + 4 * st;
#pragma unroll
    for (int xc = 0; xc < 2; ++xc) {
      int x = x0 + xc * 16 + lr;
#pragma unroll
      for (int mi = 0; mi < 2; ++mi)
#pragma unroll
        for (int r2 = 0; r2 < 4; ++r2) {
          int p = pe[mi][r2];
          int dy = y - Yp[mi][r2];
          int dx = x - Xp[mi][r2];
          if (p >= 0 && (unsigned)dy < 10u && (unsigned)dx < 10u)
            wl[(size_t)(dy * 10 + dx) * NPIX + p] =
                (f16)(acc[st * 2 + xc][mi][r2] * 0.0625f);
        }
    }
  }
}

// ---------------------------------------------------------------------------
// 4) bilinear sampling from compact corner buffer W[lev*100+dy*10+dx][m].
// ---------------------------------------------------------------------------
__global__ __launch_bounds__(256) void corr_sample(const f16* __restrict__ Wbuf,
                                                   const float* __restrict__ coords,
                                                   float* __restrict__ out) {
  int bx = blockIdx.x;            // 288 = 8 xcd * 36
  int xcd = bx & 7;
  int idx = bx >> 3;              // 0..35
  int j = idx % 9;                // window row
  int mc = xcd + 8 * (idx / 9);   // m-chunk 0..31
  int m = mc * 256 + threadIdx.x;
  int lev = blockIdx.z;
  int Hl = H0 >> lev, Wl = W0 >> lev;

  float cx = coords[m];
  float cy = coords[NPIX + m];
  float inv = 1.0f / (float)(1 << lev);
  float xb = cx * inv, yb = cy * inv;
  float fx = floorf(xb), fy = floorf(yb);
  int X0 = (int)fx - 4, Y0 = (int)fy - 4;   // matches bucket_build meta exactly
  float wx1 = xb - fx, wx0 = 1.0f - wx1;
  float wy1 = yb - fy, wy0 = 1.0f - wy1;

  const f16* wb = Wbuf + (size_t)(lev * 100) * NPIX + m;
  float* op = out + ((size_t)lev * 81 + (size_t)j * 9) * NPIX + m;

  float cur[10], nxt[10];
  auto loadrow = [&](float* row, int jr) {
    int y = Y0 + jr;
    bool yin = (unsigned)y < (unsigned)Hl;
#pragma unroll
    for (int i = 0; i < 10; ++i) {
      int x = X0 + i;
      bool in = yin && ((unsigned)x < (unsigned)Wl);
      row[i] = in ? (float)wb[(size_t)(jr * 10 + i) * NPIX] : 0.0f;
    }
  };
  loadrow(cur, j);
  loadrow(nxt, j + 1);
#pragma unroll
  for (int i = 0; i < 9; ++i) {
    float v = wy0 * (wx0 * cur[i] + wx1 * cur[i + 1])
            + wy1 * (wx0 * nxt[i] + wx1 * nxt[i + 1]);
    op[(size_t)i * NPIX] = v;
  }
}

// ---------------------------------------------------------------------------
extern "C" void kernel_launch(void* const* d_in, const int* in_sizes, int n_in,
                              void* d_out, int out_size, void* d_ws, size_t ws_size,
                              hipStream_t stream) {
  const float* fmap1  = (const float*)d_in[0];   // [1,256,64,128]
  const float* fmap2  = (const float*)d_in[1];
  const float* coords = (const float*)d_in[2];   // [1,2,64,128]
  float* out = (float*)d_out;                    // [1,324,64,128] fp32

  char* ws = (char*)d_ws;
  size_t offA = 0;
  size_t offB = offA + (size_t)NPIX * KD * 2;    // At: 4 MB
  size_t offW = offB + (size_t)NCAT * KD * 2;    // Bt: 5.57 MB
  size_t offM = offW + (size_t)400 * NPIX * 2;   // W: 6.55 MB
  size_t offC = offM + (size_t)NPIX * 8;         // meta: 64 KB
  size_t need = offC + (size_t)ZTOT * 4;         // cnt+plist: ~148 KB
  if (ws_size < need) return;

  f16*  At   = (f16*)(ws + offA);
  f16*  Bt   = (f16*)(ws + offB);
  f16*  Wbuf = (f16*)(ws + offW);
  int2* meta = (int2*)(ws + offM);
  int*  cnt  = (int*)(ws + offC);

  fused_pre<<<1505, 256, 0, stream>>>(fmap1, fmap2, At, Bt, cnt);
  bucket_build<<<8, 1024, 0, stream>>>(coords, meta, cnt);
  gemm_all<<<2464, 256, 0, stream>>>(At, Bt, cnt, meta, Wbuf);
  corr_sample<<<dim3(288, 1, 4), 256, 0, stream>>>(Wbuf, coords, out);
}

// Round 12
// 73.355 us; speedup vs baseline: 1.8047x; 1.1237x over previous
//
#include <hip/hip_runtime.h>
#include <stdint.h>

typedef _Float16 f16;
typedef __attribute__((ext_vector_type(8))) _Float16 f16x8;
typedef __attribute__((ext_vector_type(4))) float f32x4;
typedef __attribute__((ext_vector_type(2))) float fv2;
typedef __attribute__((ext_vector_type(4))) float fv4;

#define H0 64
#define W0 128
#define NPIX 8192   // H0*W0
#define KD 256
#define NCAT 10880  // 8192 + 2048 + 512 + 128
#define OFF1 8192
#define OFF2 10240
#define OFF3 10752
#define CAP0 640
#define CAP1 2048
#define PL1OFF (32 * CAP0)          // 20480 ints
#define PLTOT (PL1OFF + 8 * CAP1)   // 36864 ints
#define ZTOT (64 + PLTOT + 64)      // cnt(64) + plist + pad

// Operand layout: X[kk][row][32] (frag-native).  W layout: PIXEL-MAJOR,
// W[m][lev*128 + dy*12 + dx] (1KB/pixel) so epilogue stores are contiguous
// per 16-lane group and corr_sample reads 4x f16x8 per (m,lev).

// ---------------------------------------------------------------------------
// 1) fused pre-pass: transpose+cvt both fmaps into frag layout, pooled
//    feature rows, zero cnt+plist. grid = 1024 + 336 + 145 = 1505
// ---------------------------------------------------------------------------
__global__ __launch_bounds__(256) void fused_pre(const float* __restrict__ in0,
                                                 const float* __restrict__ in1,
                                                 f16* __restrict__ At,
                                                 f16* __restrict__ Bt,
                                                 int* __restrict__ cnt) {
  __shared__ f16 tile[64][65];
  int bid = blockIdx.x;
  int t = threadIdx.x;

  if (bid < 1024) {                       // ---- transpose + cvt ----
    const float* in = (bid < 512) ? in0 : in1;
    f16* out = (bid < 512) ? At : Bt;
    size_t NR = (bid < 512) ? NPIX : NCAT;
    int bx = bid & 511;
    int m0 = (bx & 127) * 64;
    int d0 = (bx >> 7) * 64;
    int a = t & 63, b = t >> 6;
#pragma unroll
    for (int i = 0; i < 16; ++i) {
      int d = b + i * 4;
      tile[a][d] = (f16)in[(size_t)(d0 + d) * NPIX + m0 + a];
    }
    __syncthreads();
#pragma unroll
    for (int i = 0; i < 16; ++i) {
      int m = b + i * 4;
      int d = d0 + a;
      out[((size_t)(d >> 5) * NR + (m0 + m)) * 32 + (d & 31)] = tile[m][a];
    }
  } else if (bid < 1360) {                // ---- pooled feature rows ----
    int idx = (bid - 1024) * 256 + t;     // 0..86015
    float acc[8] = {0, 0, 0, 0, 0, 0, 0, 0};
    int r, dc;
    if (idx < 65536) {                    // lev1: 2048 rows, 2x2
      int r1 = idx & 2047; dc = idx >> 11; r = r1;
      int y = r1 >> 6, x = r1 & 63;
#pragma unroll
      for (int e = 0; e < 8; ++e) {
        const float* p = in1 + (size_t)(dc * 8 + e) * NPIX + (y * 2) * W0 + x * 2;
        fv2 s0 = *(const fv2*)p;
        fv2 s1 = *(const fv2*)(p + W0);
        acc[e] = (s0[0] + s0[1] + s1[0] + s1[1]) * 0.25f;
      }
    } else if (idx < 81920) {             // lev2: 512 rows, 4x4
      int i2 = idx - 65536;
      int r2 = i2 & 511; dc = i2 >> 9; r = 2048 + r2;
      int y = r2 >> 5, x = r2 & 31;
#pragma unroll
      for (int e = 0; e < 8; ++e) {
        const float* p = in1 + (size_t)(dc * 8 + e) * NPIX + (y * 4) * W0 + x * 4;
        float s = 0.f;
#pragma unroll
        for (int h = 0; h < 4; ++h) {
          fv4 v = *(const fv4*)(p + h * W0);
          s += v[0] + v[1] + v[2] + v[3];
        }
        acc[e] = s * 0.0625f;
      }
    } else {                              // lev3: 128 rows, 8x8
      int i3 = idx - 81920;
      int r3 = i3 & 127; dc = i3 >> 7; r = 2560 + r3;
      int y = r3 >> 4, x = r3 & 15;
#pragma unroll
      for (int e = 0; e < 8; ++e) {
        const float* p = in1 + (size_t)(dc * 8 + e) * NPIX + (y * 8) * W0 + x * 8;
        float s = 0.f;
#pragma unroll
        for (int h = 0; h < 8; ++h) {
          fv4 v0 = *(const fv4*)(p + h * W0);
          fv4 v1 = *(const fv4*)(p + h * W0 + 4);
          s += v0[0] + v0[1] + v0[2] + v0[3] + v1[0] + v1[1] + v1[2] + v1[3];
        }
        acc[e] = s * 0.015625f;
      }
    }
    f16x8 o;
#pragma unroll
    for (int e = 0; e < 8; ++e) o[e] = (f16)acc[e];
    *(f16x8*)(Bt + ((size_t)(dc >> 2) * NCAT + 8192 + r) * 32 + (dc & 3) * 8) = o;
  } else {                                // ---- zero cnt + plist ----
    int idx = (bid - 1360) * 256 + t;
    if (idx < ZTOT) cnt[idx] = 0;
  }
}

// ---------------------------------------------------------------------------
// 2) bucket build, LDS-aggregated: 8 blocks x 1024 thr; one global atomic
//    per (block,bucket); exact-slot scatter. Deterministic set.
// ---------------------------------------------------------------------------
__global__ __launch_bounds__(1024) void bucket_build(const float* __restrict__ coords,
                                                     int2* __restrict__ meta,
                                                     int* __restrict__ cnt) {
  __shared__ int hist[40];
  __shared__ int base[40];
  int* plist = cnt + 64;
  int t = threadIdx.x;
  int m = blockIdx.x * 1024 + t;
  if (t < 40) hist[t] = 0;
  __syncthreads();

  float cx = coords[m];
  float cy = coords[NPIX + m];
  int X0l[2], Y0l[2];
  int mx = 0, my = 0;
#pragma unroll
  for (int lev = 0; lev < 4; ++lev) {
    float inv = 1.0f / (float)(1 << lev);
    int X0 = (int)floorf(cx * inv) - 4;     // identical expr in corr_sample
    int Y0 = (int)floorf(cy * inv) - 4;
    if (lev < 2) { X0l[lev] = X0; Y0l[lev] = Y0; }
    mx |= (X0 & 0xff) << (8 * lev);
    my |= (Y0 & 0xff) << (8 * lev);
  }
  meta[m] = make_int2(mx, my);

  int b0 = (min(max(Y0l[0], 0), 63) >> 4) * 8 + (min(max(X0l[0], 0), 127) >> 4);
  int b1 = (min(max(Y0l[1], 0), 31) >> 4) * 4 + (min(max(X0l[1], 0), 63) >> 4);
  int s0 = atomicAdd(&hist[b0], 1);
  int s1 = atomicAdd(&hist[32 + b1], 1);
  __syncthreads();

  if (t < 40) base[t] = atomicAdd(&cnt[t], hist[t]);
  __syncthreads();

  int p0 = base[b0] + s0;
  if (p0 < CAP0) plist[b0 * CAP0 + p0] = m;
  int p1 = base[32 + b1] + s1;
  if (p1 < CAP1) plist[PL1OFF + b1 * CAP1 + p1] = m;
}

// ---------------------------------------------------------------------------
// 3) merged GEMM: bid<160 dense (lev 2+3); else bucketed (lev 0+1) with A
//    staged once in swizzled LDS and pixel-major W stores.
// ---------------------------------------------------------------------------
__global__ __launch_bounds__(256, 2) void gemm_all(const f16* __restrict__ At,
                                                   const f16* __restrict__ Bt,
                                                   const int* __restrict__ cnt,
                                                   const int2* __restrict__ meta,
                                                   f16* __restrict__ Wbuf) {
  __shared__ f16 sa[8192];   // 16KB: 32 pixels x 8 kk x 32 f16, XOR-swizzled
  const int* plist = cnt + 64;
  int bid = blockIdx.x;      // 160 dense + 2304 bucket = 2464
  int t = threadIdx.x;
  int lane = t & 63;
  int w = t >> 6;
  int lr = lane & 15;
  int ko = lane >> 4;

  if (bid < 160) {
    // ================= dense path: levels 2+3 =================
    int bm = (((bid & 7) << 2) | ((bid >> 3) & 3)) << 8;
    int bn = OFF2 + ((bid >> 5) << 7);

    const f16* Ab = At + (size_t)(bm + w * 64 + lr) * 32 + ko * 8;
    const f16* Bb = Bt + (size_t)(bn + lr) * 32 + ko * 8;

    f16x8 af[2][4], bf[2][8];
#define LOADK(s, kk)                                                           \
    do {                                                                       \
      const f16* ap = Ab + (size_t)(kk) * (NPIX * 32);                         \
      const f16* bp = Bb + (size_t)(kk) * (NCAT * 32);                         \
      _Pragma("unroll")                                                        \
      for (int i = 0; i < 4; ++i) af[s][i] = *(const f16x8*)(ap + i * 512);    \
      _Pragma("unroll")                                                        \
      for (int i = 0; i < 8; ++i) bf[s][i] = *(const f16x8*)(bp + i * 512);    \
    } while (0)

    f32x4 acc[4][8];
#pragma unroll
    for (int i = 0; i < 4; ++i)
#pragma unroll
      for (int j = 0; j < 8; ++j) acc[i][j] = (f32x4){0.f, 0.f, 0.f, 0.f};

    LOADK(0, 0);
    LOADK(1, 1);
#pragma unroll
    for (int kk = 0; kk < 8; ++kk) {
      const int cur = kk & 1;
#pragma unroll
      for (int mi = 0; mi < 4; ++mi)
#pragma unroll
        for (int ni = 0; ni < 8; ++ni)
          acc[mi][ni] = __builtin_amdgcn_mfma_f32_16x16x32_f16(
              af[cur][mi], bf[cur][ni], acc[mi][ni], 0, 0, 0);
      if (kk + 2 < 8) LOADK(cur, kk + 2);
    }
#undef LOADK

    int lev, n0, wlog;
    if (bn < OFF3) { lev = 2; n0 = bn - OFF2; wlog = 5; }
    else           { lev = 3; n0 = bn - OFF3; wlog = 4; }
    int wmask = (1 << wlog) - 1;
    int yA = n0 >> wlog;
    int yB = (n0 + 127) >> wlog;
    int ycol[8], xcol[8];
#pragma unroll
    for (int ni = 0; ni < 8; ++ni) {
      int n = n0 + ni * 16 + lr;
      ycol[ni] = n >> wlog;
      xcol[ni] = n & wmask;
    }
    int sh = lev * 8;
#pragma unroll
    for (int mi = 0; mi < 4; ++mi)
#pragma unroll
      for (int r2 = 0; r2 < 4; ++r2) {
        int grow = bm + w * 64 + mi * 16 + ko * 4 + r2;
        int2 mv = meta[grow];
        int Y0 = (int)(signed char)((mv.y >> sh) & 0xff);
        if (Y0 <= yB && Y0 + 9 >= yA) {
          int X0 = (int)(signed char)((mv.x >> sh) & 0xff);
          f16* rowp = Wbuf + (size_t)grow * 512 + lev * 128;
#pragma unroll
          for (int ni = 0; ni < 8; ++ni) {
            int dy = ycol[ni] - Y0;
            int dx = xcol[ni] - X0;
            if ((unsigned)dy < 10u && (unsigned)dx < 10u)
              rowp[dy * 12 + dx] = (f16)(acc[mi][ni][r2] * 0.0625f);
          }
        }
      }
    return;
  }

  // ================= bucket path: levels 0+1 =================
  int bb = bid - 160;
  int lev, b, mg, half;
  if (bb < 1280) { lev = 0; b = bb / 40; int r = bb % 40; mg = r >> 1; half = r & 1; }
  else { lev = 1; int i = bb - 1280; b = i / 128; int r = i % 128; mg = r >> 1; half = r & 1; }

  int CAP   = lev ? CAP1 : CAP0;
  int cb    = min(cnt[lev ? 32 + b : b], CAP);
  if (mg * 32 >= cb) return;
  int Hl    = lev ? 32 : 64;
  int Wmap  = lev ? 64 : 128;
  int bx    = lev ? (b & 3) : (b & 7);
  int by    = lev ? (b >> 2) : (b >> 3);
  int x0 = bx * 16, y0 = by * 16;
  int NY = min(25, Hl - y0);
  int rowbase = lev ? 8192 : 0;
  int pbase = (lev ? PL1OFF + b * CAP1 : b * CAP0) + mg * 32;

  // ---- stage the 32 A-pixel rows into swizzled LDS (once) ----
  {
    int spix = t >> 3;                 // 0..31
    int skk  = t & 7;                  // kk plane
    int sp = plist[pbase + spix] & (NPIX - 1);
    const f16* g = At + (size_t)skk * (NPIX * 32) + (size_t)sp * 32;  // 64B
    int line = spix >> 1;
    int sb = (spix & 1) * 4;
    f16* dst = sa + skk * 1024 + line * 64;
#pragma unroll
    for (int q = 0; q < 4; ++q) {
      int phys = (sb + q) ^ (line & 7);
      *(f16x8*)(dst + phys * 8) = *(const f16x8*)(g + q * 8);
    }
  }

  // af LDS read offsets (swizzle-matched)
  int aoff[2];
#pragma unroll
  for (int mi = 0; mi < 2; ++mi) {
    int pl = mi * 16 + lr;
    int line = pl >> 1;
    int phys = ((pl & 1) * 4 + ko) ^ (line & 7);
    aoff[mi] = line * 64 + phys * 8;
  }

  bool vst[4];
  int brow[4];
#pragma unroll
  for (int st = 0; st < 4; ++st) {
    int q = w + 4 * st;
    int yl = half * 13 + q;
    vst[st] = (q < (half ? 12 : 13)) && (yl < NY);
    int ylc = min(yl, NY - 1);
    brow[st] = rowbase + (y0 + ylc) * Wmap + x0 + lr;
  }

  f16x8 bf[2][8];
#define BLDB(s_, kk_)                                                          \
  do {                                                                         \
    const f16* bp = Bt + (size_t)(kk_) * (NCAT * 32) + ko * 8;                 \
    _Pragma("unroll")                                                          \
    for (int st = 0; st < 4; ++st) {                                           \
      bf[s_][st * 2]     = *(const f16x8*)(bp + (size_t)brow[st] * 32);        \
      bf[s_][st * 2 + 1] = *(const f16x8*)(bp + (size_t)(brow[st] + 16) * 32); \
    }                                                                          \
  } while (0)

  BLDB(0, 0);
  BLDB(1, 1);

  f32x4 acc[8][2];
#pragma unroll
  for (int i = 0; i < 8; ++i)
#pragma unroll
    for (int j = 0; j < 2; ++j) acc[i][j] = (f32x4){0.f, 0.f, 0.f, 0.f};

  __syncthreads();   // sa staged (also covers bf[0] via program order deps)

#pragma unroll
  for (int kk = 0; kk < 8; ++kk) {
    const int cur = kk & 1;
    f16x8 a0 = *(const f16x8*)(sa + kk * 1024 + aoff[0]);
    f16x8 a1 = *(const f16x8*)(sa + kk * 1024 + aoff[1]);
#pragma unroll
    for (int nf = 0; nf < 8; ++nf) {
      acc[nf][0] = __builtin_amdgcn_mfma_f32_16x16x32_f16(a0, bf[cur][nf],
                                                          acc[nf][0], 0, 0, 0);
      acc[nf][1] = __builtin_amdgcn_mfma_f32_16x16x32_f16(a1, bf[cur][nf],
                                                          acc[nf][1], 0, 0, 0);
    }
    if (kk + 2 < 8) BLDB(cur, kk + 2);
  }
#undef BLDB

  // ---- scatter into pixel-major W (contiguous per 16-lane group) ----
  int pe[2][4];
  int Xp[2][4], Yp[2][4];
  int sh = lev * 8;
#pragma unroll
  for (int mi = 0; mi < 2; ++mi)
#pragma unroll
    for (int r2 = 0; r2 < 4; ++r2) {
      int slot = mg * 32 + mi * 16 + ko * 4 + r2;
      int p = plist[pbase + mi * 16 + ko * 4 + r2] & (NPIX - 1);
      pe[mi][r2] = (slot < cb) ? p : -1;
      int2 mv = meta[p];
      Xp[mi][r2] = (int)(signed char)((mv.x >> sh) & 0xff);
      Yp[mi][r2] = (int)(signed char)((mv.y >> sh) & 0xff);
    }
#pragma unroll
  for (int st = 0; st < 4; ++st) {
    if (!vst[st]) continue;
    int y = y0 + half * 13 + w + 4 * st;
#pragma unroll
    for (int xc = 0; xc < 2; ++xc) {
      int x = x0 + xc * 16 + lr;
#pragma unroll
      for (int mi = 0; mi < 2; ++mi)
#pragma unroll
        for (int r2 = 0; r2 < 4; ++r2) {
          int p = pe[mi][r2];
          int dy = y - Yp[mi][r2];
          int dx = x - Xp[mi][r2];
          if (p >= 0 && (unsigned)dy < 10u && (unsigned)dx < 10u)
            Wbuf[(size_t)p * 512 + lev * 128 + dy * 12 + dx] =
                (f16)(acc[st * 2 + xc][mi][r2] * 0.0625f);
        }
    }
  }
}

// ---------------------------------------------------------------------------
// 4) bilinear sampling from pixel-major W: 4x f16x8 loads per (m,lev),
//    all 81 taps per thread, coalesced fp32 stores. 512 blocks x 64 thr.
// ---------------------------------------------------------------------------
__global__ __launch_bounds__(64) void corr_sample(const f16* __restrict__ Wbuf,
                                                  const float* __restrict__ coords,
                                                  float* __restrict__ out) {
  int tid = blockIdx.x * 64 + threadIdx.x;   // 32768
  int m = tid & (NPIX - 1);
  int lev = tid >> 13;
  int Hl = H0 >> lev, Wl = W0 >> lev;

  float cx = coords[m];
  float cy = coords[NPIX + m];
  float inv = 1.0f / (float)(1 << lev);
  float xb = cx * inv, yb = cy * inv;
  float fx = floorf(xb), fy = floorf(yb);
  int X0 = (int)fx - 4, Y0 = (int)fy - 4;   // matches bucket_build meta exactly
  float wx1 = xb - fx, wx0 = 1.0f - wx1;
  float wy1 = yb - fy, wy0 = 1.0f - wy1;

  const f16* wb = Wbuf + (size_t)m * 512 + lev * 128;
  f16x8 rv[15];                              // 120 f16, max index 118
#pragma unroll
  for (int i = 0; i < 15; ++i) rv[i] = *(const f16x8*)(wb + i * 8);

  float* op = out + (size_t)lev * 81 * NPIX + m;
  float cur[11], nxt[11];
#pragma unroll
  for (int i = 0; i < 11; ++i) {
    bool in = ((unsigned)Y0 < (unsigned)Hl) && ((unsigned)(X0 + i) < (unsigned)Wl);
    cur[i] = in ? (float)rv[i >> 3][i & 7] : 0.0f;
  }
#pragma unroll
  for (int j = 0; j < 9; ++j) {
    bool yin = (unsigned)(Y0 + j + 1) < (unsigned)Hl;
#pragma unroll
    for (int i = 0; i < 11; ++i) {
      int c = (j + 1) * 12 + i;
      bool in = yin && ((unsigned)(X0 + i) < (unsigned)Wl);
      nxt[i] = in ? (float)rv[c >> 3][c & 7] : 0.0f;
    }
#pragma unroll
    for (int i = 0; i < 9; ++i) {
      float v = wy0 * (wx0 * cur[i] + wx1 * cur[i + 1])
              + wy1 * (wx0 * nxt[i] + wx1 * nxt[i + 1]);
      op[(size_t)(j * 9 + i) * NPIX] = v;
    }
#pragma unroll
    for (int i = 0; i < 11; ++i) cur[i] = nxt[i];
  }
}

// ---------------------------------------------------------------------------
extern "C" void kernel_launch(void* const* d_in, const int* in_sizes, int n_in,
                              void* d_out, int out_size, void* d_ws, size_t ws_size,
                              hipStream_t stream) {
  const float* fmap1  = (const float*)d_in[0];   // [1,256,64,128]
  const float* fmap2  = (const float*)d_in[1];
  const float* coords = (const float*)d_in[2];   // [1,2,64,128]
  float* out = (float*)d_out;                    // [1,324,64,128] fp32

  char* ws = (char*)d_ws;
  size_t offA = 0;
  size_t offB = offA + (size_t)NPIX * KD * 2;    // At: 4 MB
  size_t offW = offB + (size_t)NCAT * KD * 2;    // Bt: 5.57 MB
  size_t offM = offW + (size_t)NPIX * 512 * 2;   // W: 8 MB (pixel-major)
  size_t offC = offM + (size_t)NPIX * 8;         // meta: 64 KB
  size_t need = offC + (size_t)ZTOT * 4;         // cnt+plist: ~148 KB
  if (ws_size < need) return;

  f16*  At   = (f16*)(ws + offA);
  f16*  Bt   = (f16*)(ws + offB);
  f16*  Wbuf = (f16*)(ws + offW);
  int2* meta = (int2*)(ws + offM);
  int*  cnt  = (int*)(ws + offC);

  fused_pre<<<1505, 256, 0, stream>>>(fmap1, fmap2, At, Bt, cnt);
  bucket_build<<<8, 1024, 0, stream>>>(coords, meta, cnt);
  gemm_all<<<2464, 256, 0, stream>>>(At, Bt, cnt, meta, Wbuf);
  corr_sample<<<512, 64, 0, stream>>>(Wbuf, coords, out);
}